// Round 10
// baseline (548.917 us; speedup 1.0000x reference)
//
#include <hip/hip_runtime.h>
#include <stdint.h>

// ---------- bf16 helpers (storage = unsigned short) ----------
__device__ __forceinline__ float b2f(unsigned short u) {
    union { uint32_t i; float f; } v; v.i = ((uint32_t)u) << 16; return v.f;
}
__device__ __forceinline__ unsigned short f2b(float f) {
    union { float f; uint32_t i; } v; v.f = f;
    uint32_t r = v.i + 0x7fffu + ((v.i >> 16) & 1u);   // RNE
    return (unsigned short)(r >> 16);
}

typedef __bf16 bf16x8 __attribute__((ext_vector_type(8)));
typedef float  f32x4  __attribute__((ext_vector_type(4)));

// ---------------------------------------------------------------------------
// cvt: xb = bf16(x), 8 elems/thread.
// ---------------------------------------------------------------------------
__global__ __launch_bounds__(256)
void cvt_f32_bf16(const float* __restrict__ x, unsigned short* __restrict__ xb) {
    int t = blockIdx.x * 256 + threadIdx.x;
    const float4* p = (const float4*)(x + (size_t)t * 8);
    float4 f0 = p[0], f1 = p[1];
    int4 o;
    o.x = (uint32_t)f2b(f0.x) | ((uint32_t)f2b(f0.y) << 16);
    o.y = (uint32_t)f2b(f0.z) | ((uint32_t)f2b(f0.w) << 16);
    o.z = (uint32_t)f2b(f1.x) | ((uint32_t)f2b(f1.y) << 16);
    o.w = (uint32_t)f2b(f1.z) | ((uint32_t)f2b(f1.w) << 16);
    ((int4*)xb)[t] = o;
}

// ---------------------------------------------------------------------------
// build_T: T[rm=(r1*16+n2)*16+m2][n3][m3] = sum_r2 c1[rm][r2]*c2[(r2*N3+n3)*M3+m3]
// ---------------------------------------------------------------------------
template<int N3, int M3>
__global__ void build_T(const float* __restrict__ c1,
                        const float* __restrict__ c2,
                        float* __restrict__ T) {
    int e = blockIdx.x * 256 + threadIdx.x;
    int m3 = e % M3;
    int t  = e / M3;
    int n3 = t % N3;
    int rm = t / N3;
    float s = 0.f;
#pragma unroll
    for (int r2 = 0; r2 < 16; ++r2)
        s += c1[rm * 16 + r2] * c2[(r2 * N3 + n3) * M3 + m3];
    T[e] = s;
}

// ---------------------------------------------------------------------------
// build_W (coalesced remap): thread t = (((n1*M1+m1)*N2+n2)*M2+m2)*M3+m3.
// ---------------------------------------------------------------------------
template<int N1, int N2, int N3, int M1, int M2, int M3>
__global__ __launch_bounds__(256)
void build_W(const float* __restrict__ c0,
             const float* __restrict__ T,
             unsigned short* __restrict__ W) {
    constexpr int K = N1 * N2 * N3;
    int t  = blockIdx.x * 256 + threadIdx.x;
    int m3 = t % M3;
    int m2 = (t / M3) % M2;
    int n2 = (t / (M3 * M2)) % N2;
    int m1 = (t / (M3 * M2 * N2)) % M1;
    int n1 =  t / (M3 * M2 * N2 * M1);

    float c0r[16];
    const float4* c0p = (const float4*)(c0 + (n1 * M1 + m1) * 16);
#pragma unroll
    for (int i = 0; i < 4; ++i) ((float4*)c0r)[i] = c0p[i];

    float acc[N3] = {};
#pragma unroll
    for (int r1 = 0; r1 < 16; ++r1) {
        const float* Tp = T + (size_t)(((r1 * 16 + n2) * 16 + m2) * N3) * M3 + m3;
#pragma unroll
        for (int n3 = 0; n3 < N3; ++n3)
            acc[n3] += c0r[r1] * Tp[n3 * M3];
    }

    unsigned short ob[N3];
#pragma unroll
    for (int n3 = 0; n3 < N3; ++n3) ob[n3] = f2b(acc[n3]);

    unsigned short* dst = W + (size_t)((m1 * M2 + m2) * M3 + m3) * K
                            + (n1 * N2 + n2) * N3;
#pragma unroll
    for (int c = 0; c < N3 / 8; ++c)
        ((int4*)dst)[c] = ((const int4*)ob)[c];
}

// ---------------------------------------------------------------------------
// GEMM (double-buffered): C[M][N] = A[M][K]*Bt[N][K]^T + bias[N], opt. GELU.
// BM=64 x BN=128, BK=64, 4 waves (2x2), wave tile 32x64 = 2x4 MFMA 16x16x32.
// K-loop: load_regs(k+1) -> compute(cur) -> store_lds(1-cur) -> barrier.
// One barrier/iter; global loads in flight during MFMA (latency hidden).
// Register staging only (global_load_lds corrupts at >4 blocks/CU — R7/R8).
// XOR-swizzled LDS (conflict-free, R6-verified).
// ---------------------------------------------------------------------------
template<int BM, int BN, int KTOT, bool DO_GELU, bool A_F32, bool C_F32>
__global__ __launch_bounds__(256)
void gemm_bias_act(const void* __restrict__ Av,
                   const unsigned short* __restrict__ Bt,
                   const float* __restrict__ bias,
                   void* __restrict__ Cv,
                   int Ncols) {
    constexpr int BK  = 64;
    constexpr int FI  = BM / 32;
    constexpr int FJ  = BN / 32;
    constexpr int ASZ = BM * BK;
    constexpr int BSZ = BN * BK;
    __shared__ unsigned short As[2 * ASZ];
    __shared__ unsigned short Bs[2 * BSZ];

    const int tid  = threadIdx.x;
    const int lane = tid & 63;
    const int wave = tid >> 6;
    const int rowBase = blockIdx.y * BM;
    const int colBase = blockIdx.x * BN;

    const int waveM = (wave >> 1) * (BM / 2);
    const int waveN = (wave & 1) * (BN / 2);

    f32x4 acc[FI][FJ] = {};
    int4 aReg[FI], bReg[FJ];

    const int lr    = lane >> 3;          // local row within 8-row chunk
    const int jj    = lane & 7;           // LDS store chunk
    const int jglob = jj ^ lr;            // swizzled global chunk
    const int mrow  = lane & 15;
    const int kc    = lane >> 4;          // 0..3
    const int rkey  = mrow & 7;

    auto load_tile = [&](int k0) {
#pragma unroll
        for (int it = 0; it < FI; ++it) {
            const int c = wave * FI + it;
            const size_t aoff = (size_t)(rowBase + c * 8 + lr) * KTOT + k0 + jglob * 8;
            if (A_F32) {
                const float* ga = (const float*)Av + aoff;
                float4 f0 = *(const float4*)ga;
                float4 f1 = *(const float4*)(ga + 4);
                int4 p;
                p.x = (uint32_t)f2b(f0.x) | ((uint32_t)f2b(f0.y) << 16);
                p.y = (uint32_t)f2b(f0.z) | ((uint32_t)f2b(f0.w) << 16);
                p.z = (uint32_t)f2b(f1.x) | ((uint32_t)f2b(f1.y) << 16);
                p.w = (uint32_t)f2b(f1.z) | ((uint32_t)f2b(f1.w) << 16);
                aReg[it] = p;
            } else {
                aReg[it] = *(const int4*)((const unsigned short*)Av + aoff);
            }
        }
#pragma unroll
        for (int it = 0; it < FJ; ++it) {
            const int c = wave * FJ + it;
            bReg[it] = *(const int4*)(Bt + (size_t)(colBase + c * 8 + lr) * KTOT + k0 + jglob * 8);
        }
    };

    auto store_tile = [&](int buf) {
#pragma unroll
        for (int it = 0; it < FI; ++it) {
            const int c = wave * FI + it;
            *(int4*)&As[buf * ASZ + c * 512 + lane * 8] = aReg[it];
        }
#pragma unroll
        for (int it = 0; it < FJ; ++it) {
            const int c = wave * FJ + it;
            *(int4*)&Bs[buf * BSZ + c * 512 + lane * 8] = bReg[it];
        }
    };

    auto compute = [&](int buf) {
#pragma unroll
        for (int ks = 0; ks < 2; ++ks) {
            const int jswz = ((ks * 4 + kc) ^ rkey) * 8;
            bf16x8 a_f[FI], b_f[FJ];
#pragma unroll
            for (int i = 0; i < FI; ++i)
                a_f[i] = *(const bf16x8*)&As[buf * ASZ + (waveM + i * 16 + mrow) * BK + jswz];
#pragma unroll
            for (int j = 0; j < FJ; ++j)
                b_f[j] = *(const bf16x8*)&Bs[buf * BSZ + (waveN + j * 16 + mrow) * BK + jswz];
#pragma unroll
            for (int i = 0; i < FI; ++i)
#pragma unroll
                for (int j = 0; j < FJ; ++j)
                    acc[i][j] = __builtin_amdgcn_mfma_f32_16x16x32_bf16(
                        a_f[i], b_f[j], acc[i][j], 0, 0, 0);
        }
    };

    // Prologue
    load_tile(0);
    store_tile(0);
    __syncthreads();

    int cur = 0;
    for (int k0 = BK; k0 < KTOT; k0 += BK) {
        load_tile(k0);           // global loads for k0 in flight during compute
        compute(cur);
        store_tile(cur ^ 1);     // implicit vmcnt wait lands here, after MFMA
        __syncthreads();         // single barrier per iteration
        cur ^= 1;
    }
    compute(cur);

    // Epilogue: C/D layout col(n)=lane&15, row(m)=(lane>>4)*4+reg
    const int cRow = (lane >> 4) * 4;
    const int cCol = lane & 15;
#pragma unroll
    for (int i = 0; i < FI; ++i) {
#pragma unroll
        for (int j = 0; j < FJ; ++j) {
            const int col = colBase + waveN + j * 16 + cCol;
            const float bv = bias[col];
#pragma unroll
            for (int r = 0; r < 4; ++r) {
                const int row = rowBase + waveM + i * 16 + cRow + r;
                float z = acc[i][j][r] + bv;
                if (DO_GELU)
                    z = 0.5f * z * (1.f + erff(z * 0.70710678118654752f));
                const size_t off = (size_t)row * Ncols + col;
                if (C_F32) ((float*)Cv)[off] = z;
                else       ((unsigned short*)Cv)[off] = f2b(z);
            }
        }
    }
}

// ---------------------------------------------------------------------------
extern "C" void kernel_launch(void* const* d_in, const int* in_sizes, int n_in,
                              void* d_out, int out_size, void* d_ws, size_t ws_size,
                              hipStream_t stream) {
    const float* x      = (const float*)d_in[0];   // [4096,1024] fp32
    const float* fc1_c0 = (const float*)d_in[1];
    const float* fc1_c1 = (const float*)d_in[2];
    const float* fc1_c2 = (const float*)d_in[3];
    const float* fc1_b  = (const float*)d_in[4];
    const float* fc2_c0 = (const float*)d_in[5];
    const float* fc2_c1 = (const float*)d_in[6];
    const float* fc2_c2 = (const float*)d_in[7];
    const float* fc2_b  = (const float*)d_in[8];

    // Workspace layout (50 MB preferred):
    //   [0,8M)   W    bf16 — W1t [4096][1024], later W2t [1024][4096]
    //   [8,10M)  T    f32 scratch
    //   [10,18M) xb   bf16 copy of x
    //   [18,50M) h    bf16 [4096][4096]
    // Fallback (<50 MB): no xb; GEMM1 repacks fp32 A in-kernel.
    char* ws = (char*)d_ws;
    unsigned short* W  = (unsigned short*)(ws);
    float*          T  = (float*)(ws + (8u << 20));
    const bool big = ws_size >= (50ull << 20);
    unsigned short* xb = (unsigned short*)(ws + (10u << 20));
    unsigned short* h  = (unsigned short*)(ws + (big ? (18u << 20) : (10u << 20)));

    // ---- layer 1: in (8,16,8) -> out (16,16,16)
    build_T<8, 16><<<2048, 256, 0, stream>>>(fc1_c1, fc1_c2, T);
    build_W<8, 16, 8, 16, 16, 16><<<2048, 256, 0, stream>>>(fc1_c0, T, W);
    if (big) {
        cvt_f32_bf16<<<2048, 256, 0, stream>>>(x, xb);
        // GEMM1: 64x128 dbuf, grid 32x64 = 2048 blocks
        gemm_bias_act<64, 128, 1024, true, false, false>
            <<<dim3(32, 64), 256, 0, stream>>>(xb, W, fc1_b, h, 4096);
    } else {
        gemm_bias_act<64, 128, 1024, true, true, false>
            <<<dim3(32, 64), 256, 0, stream>>>(x, W, fc1_b, h, 4096);
    }

    // ---- layer 2: in (16,16,16) -> out (8,16,8)
    build_T<16, 8><<<2048, 256, 0, stream>>>(fc2_c1, fc2_c2, T);
    build_W<16, 16, 16, 8, 16, 8><<<1024, 256, 0, stream>>>(fc2_c0, T, W);
    // GEMM2: 64x128 dbuf, grid 8x64 = 512 blocks (BN back to 128: FETCH fix)
    gemm_bias_act<64, 128, 4096, false, false, true>
        <<<dim3(8, 64), 256, 0, stream>>>(h, W, fc2_b, d_out, 1024);
}

// Round 11
// 240.175 us; speedup vs baseline: 2.2855x; 2.2855x over previous
//
#include <hip/hip_runtime.h>
#include <stdint.h>

// ---------- bf16 helpers (storage = unsigned short) ----------
__device__ __forceinline__ float b2f(unsigned short u) {
    union { uint32_t i; float f; } v; v.i = ((uint32_t)u) << 16; return v.f;
}
__device__ __forceinline__ unsigned short f2b(float f) {
    union { float f; uint32_t i; } v; v.f = f;
    uint32_t r = v.i + 0x7fffu + ((v.i >> 16) & 1u);   // RNE
    return (unsigned short)(r >> 16);
}

typedef __bf16 bf16x8 __attribute__((ext_vector_type(8)));
typedef float  f32x4  __attribute__((ext_vector_type(4)));

// ---------------------------------------------------------------------------
// cvt: xb = bf16(x), 8 elems/thread.
// ---------------------------------------------------------------------------
__global__ __launch_bounds__(256)
void cvt_f32_bf16(const float* __restrict__ x, unsigned short* __restrict__ xb) {
    int t = blockIdx.x * 256 + threadIdx.x;
    const float4* p = (const float4*)(x + (size_t)t * 8);
    float4 f0 = p[0], f1 = p[1];
    int4 o;
    o.x = (uint32_t)f2b(f0.x) | ((uint32_t)f2b(f0.y) << 16);
    o.y = (uint32_t)f2b(f0.z) | ((uint32_t)f2b(f0.w) << 16);
    o.z = (uint32_t)f2b(f1.x) | ((uint32_t)f2b(f1.y) << 16);
    o.w = (uint32_t)f2b(f1.z) | ((uint32_t)f2b(f1.w) << 16);
    ((int4*)xb)[t] = o;
}

// ---------------------------------------------------------------------------
// build_T: T[rm=(r1*16+n2)*16+m2][n3][m3] = sum_r2 c1[rm][r2]*c2[(r2*N3+n3)*M3+m3]
// ---------------------------------------------------------------------------
template<int N3, int M3>
__global__ void build_T(const float* __restrict__ c1,
                        const float* __restrict__ c2,
                        float* __restrict__ T) {
    int e = blockIdx.x * 256 + threadIdx.x;
    int m3 = e % M3;
    int t  = e / M3;
    int n3 = t % N3;
    int rm = t / N3;
    float s = 0.f;
#pragma unroll
    for (int r2 = 0; r2 < 16; ++r2)
        s += c1[rm * 16 + r2] * c2[(r2 * N3 + n3) * M3 + m3];
    T[e] = s;
}

// ---------------------------------------------------------------------------
// build_W (coalesced remap): thread t = (((n1*M1+m1)*N2+n2)*M2+m2)*M3+m3.
// ---------------------------------------------------------------------------
template<int N1, int N2, int N3, int M1, int M2, int M3>
__global__ __launch_bounds__(256)
void build_W(const float* __restrict__ c0,
             const float* __restrict__ T,
             unsigned short* __restrict__ W) {
    constexpr int K = N1 * N2 * N3;
    int t  = blockIdx.x * 256 + threadIdx.x;
    int m3 = t % M3;
    int m2 = (t / M3) % M2;
    int n2 = (t / (M3 * M2)) % N2;
    int m1 = (t / (M3 * M2 * N2)) % M1;
    int n1 =  t / (M3 * M2 * N2 * M1);

    float c0r[16];
    const float4* c0p = (const float4*)(c0 + (n1 * M1 + m1) * 16);
#pragma unroll
    for (int i = 0; i < 4; ++i) ((float4*)c0r)[i] = c0p[i];

    float acc[N3] = {};
#pragma unroll
    for (int r1 = 0; r1 < 16; ++r1) {
        const float* Tp = T + (size_t)(((r1 * 16 + n2) * 16 + m2) * N3) * M3 + m3;
#pragma unroll
        for (int n3 = 0; n3 < N3; ++n3)
            acc[n3] += c0r[r1] * Tp[n3 * M3];
    }

    unsigned short ob[N3];
#pragma unroll
    for (int n3 = 0; n3 < N3; ++n3) ob[n3] = f2b(acc[n3]);

    unsigned short* dst = W + (size_t)((m1 * M2 + m2) * M3 + m3) * K
                            + (n1 * N2 + n2) * N3;
#pragma unroll
    for (int c = 0; c < N3 / 8; ++c)
        ((int4*)dst)[c] = ((const int4*)ob)[c];
}

// ---------------------------------------------------------------------------
// GEMM, double-buffered, LAMBDA-FREE (R10's lambdas escaped the prefetch
// arrays to scratch: 240 MB WRITE_SIZE. Straight-line code here).
// BM x BN tile, BK=64, 4 waves (2x2); wave tile (BM/2)x(BN/2) via FIxFJ
// 16x16x32 MFMA. One barrier/iter; prefetch loads in flight during MFMA.
// Register staging only (global_load_lds corrupts at >4 blocks/CU — R7/R8).
// XOR-swizzled LDS (conflict-free, R6-verified).
// ---------------------------------------------------------------------------
#define COMPUTE_TILE(BUF)                                                     \
    {                                                                         \
        _Pragma("unroll")                                                     \
        for (int ks = 0; ks < 2; ++ks) {                                      \
            const int jswz = ((ks * 4 + kc) ^ rkey) * 8;                      \
            bf16x8 a_f[FI], b_f[FJ];                                          \
            _Pragma("unroll")                                                 \
            for (int i = 0; i < FI; ++i)                                      \
                a_f[i] = *(const bf16x8*)&As[(BUF) * ASZ +                    \
                          (waveM + i * 16 + mrow) * BK + jswz];               \
            _Pragma("unroll")                                                 \
            for (int j = 0; j < FJ; ++j)                                      \
                b_f[j] = *(const bf16x8*)&Bs[(BUF) * BSZ +                    \
                          (waveN + j * 16 + mrow) * BK + jswz];               \
            _Pragma("unroll")                                                 \
            for (int i = 0; i < FI; ++i)                                      \
                _Pragma("unroll")                                             \
                for (int j = 0; j < FJ; ++j)                                  \
                    acc[i][j] = __builtin_amdgcn_mfma_f32_16x16x32_bf16(      \
                        a_f[i], b_f[j], acc[i][j], 0, 0, 0);                  \
        }                                                                     \
    }

template<int BM, int BN, int KTOT, bool DO_GELU, bool A_F32, bool C_F32>
__global__ __launch_bounds__(256)
void gemm_bias_act(const void* __restrict__ Av,
                   const unsigned short* __restrict__ Bt,
                   const float* __restrict__ bias,
                   void* __restrict__ Cv,
                   int Ncols) {
    constexpr int BK  = 64;
    constexpr int FI  = BM / 32;
    constexpr int FJ  = BN / 32;
    constexpr int ASZ = BM * BK;
    constexpr int BSZ = BN * BK;
    __shared__ unsigned short As[2 * ASZ];
    __shared__ unsigned short Bs[2 * BSZ];

    const int tid  = threadIdx.x;
    const int lane = tid & 63;
    const int wave = tid >> 6;
    const int rowBase = blockIdx.y * BM;
    const int colBase = blockIdx.x * BN;

    const int waveM = (wave >> 1) * (BM / 2);
    const int waveN = (wave & 1) * (BN / 2);

    f32x4 acc[FI][FJ] = {};

    const int lr    = lane >> 3;
    const int jj    = lane & 7;
    const int jglob = jj ^ lr;            // swizzled global chunk
    const int mrow  = lane & 15;
    const int kc    = lane >> 4;
    const int rkey  = mrow & 7;

    const size_t aRowOff = (size_t)(rowBase + lr) * KTOT + jglob * 8;
    const size_t bRowOff = (size_t)(colBase + lr) * KTOT + jglob * 8;

    // ---- prologue: stage tile 0 into buffer 0
    {
#pragma unroll
        for (int it = 0; it < FI; ++it) {
            const int c = wave * FI + it;
            const size_t aoff = aRowOff + (size_t)(c * 8) * KTOT;
            int4 v;
            if (A_F32) {
                const float* ga = (const float*)Av + aoff;
                float4 f0 = *(const float4*)ga;
                float4 f1 = *(const float4*)(ga + 4);
                v.x = (uint32_t)f2b(f0.x) | ((uint32_t)f2b(f0.y) << 16);
                v.y = (uint32_t)f2b(f0.z) | ((uint32_t)f2b(f0.w) << 16);
                v.z = (uint32_t)f2b(f1.x) | ((uint32_t)f2b(f1.y) << 16);
                v.w = (uint32_t)f2b(f1.z) | ((uint32_t)f2b(f1.w) << 16);
            } else {
                v = *(const int4*)((const unsigned short*)Av + aoff);
            }
            *(int4*)&As[c * 512 + lane * 8] = v;
        }
#pragma unroll
        for (int it = 0; it < FJ; ++it) {
            const int c = wave * FJ + it;
            *(int4*)&Bs[c * 512 + lane * 8] =
                *(const int4*)(Bt + bRowOff + (size_t)(c * 8) * KTOT);
        }
    }
    __syncthreads();

    int cur = 0;
    for (int k0 = BK; k0 < KTOT; k0 += BK) {
        // ---- prefetch next tile into registers (loads issue, no wait yet)
        int4 aR[FI], bR[FJ];
#pragma unroll
        for (int it = 0; it < FI; ++it) {
            const int c = wave * FI + it;
            const size_t aoff = aRowOff + (size_t)(c * 8) * KTOT + k0;
            if (A_F32) {
                const float* ga = (const float*)Av + aoff;
                float4 f0 = *(const float4*)ga;
                float4 f1 = *(const float4*)(ga + 4);
                int4 v;
                v.x = (uint32_t)f2b(f0.x) | ((uint32_t)f2b(f0.y) << 16);
                v.y = (uint32_t)f2b(f0.z) | ((uint32_t)f2b(f0.w) << 16);
                v.z = (uint32_t)f2b(f1.x) | ((uint32_t)f2b(f1.y) << 16);
                v.w = (uint32_t)f2b(f1.z) | ((uint32_t)f2b(f1.w) << 16);
                aR[it] = v;
            } else {
                aR[it] = *(const int4*)((const unsigned short*)Av + aoff);
            }
        }
#pragma unroll
        for (int it = 0; it < FJ; ++it) {
            const int c = wave * FJ + it;
            bR[it] = *(const int4*)(Bt + bRowOff + (size_t)(c * 8) * KTOT + k0);
        }

        // ---- compute current tile while prefetch is in flight
        COMPUTE_TILE(cur)

        // ---- store prefetched tile to the other buffer (vmcnt wait here)
#pragma unroll
        for (int it = 0; it < FI; ++it) {
            const int c = wave * FI + it;
            *(int4*)&As[(cur ^ 1) * ASZ + c * 512 + lane * 8] = aR[it];
        }
#pragma unroll
        for (int it = 0; it < FJ; ++it) {
            const int c = wave * FJ + it;
            *(int4*)&Bs[(cur ^ 1) * BSZ + c * 512 + lane * 8] = bR[it];
        }
        __syncthreads();
        cur ^= 1;
    }

    // ---- tail tile
    COMPUTE_TILE(cur)

    // Epilogue: C/D layout col(n)=lane&15, row(m)=(lane>>4)*4+reg
    const int cRow = (lane >> 4) * 4;
    const int cCol = lane & 15;
#pragma unroll
    for (int i = 0; i < FI; ++i) {
#pragma unroll
        for (int j = 0; j < FJ; ++j) {
            const int col = colBase + waveN + j * 16 + cCol;
            const float bv = bias[col];
#pragma unroll
            for (int r = 0; r < 4; ++r) {
                const int row = rowBase + waveM + i * 16 + cRow + r;
                float z = acc[i][j][r] + bv;
                if (DO_GELU)
                    z = 0.5f * z * (1.f + erff(z * 0.70710678118654752f));
                const size_t off = (size_t)row * Ncols + col;
                if (C_F32) ((float*)Cv)[off] = z;
                else       ((unsigned short*)Cv)[off] = f2b(z);
            }
        }
    }
}

// ---------------------------------------------------------------------------
extern "C" void kernel_launch(void* const* d_in, const int* in_sizes, int n_in,
                              void* d_out, int out_size, void* d_ws, size_t ws_size,
                              hipStream_t stream) {
    const float* x      = (const float*)d_in[0];   // [4096,1024] fp32
    const float* fc1_c0 = (const float*)d_in[1];
    const float* fc1_c1 = (const float*)d_in[2];
    const float* fc1_c2 = (const float*)d_in[3];
    const float* fc1_b  = (const float*)d_in[4];
    const float* fc2_c0 = (const float*)d_in[5];
    const float* fc2_c1 = (const float*)d_in[6];
    const float* fc2_c2 = (const float*)d_in[7];
    const float* fc2_b  = (const float*)d_in[8];

    // Workspace layout (50 MB preferred):
    //   [0,8M)   W    bf16 — W1t [4096][1024], later W2t [1024][4096]
    //   [8,10M)  T    f32 scratch
    //   [10,18M) xb   bf16 copy of x
    //   [18,50M) h    bf16 [4096][4096]
    // Fallback (<50 MB): no xb; GEMM1 repacks fp32 A in-kernel.
    char* ws = (char*)d_ws;
    unsigned short* W  = (unsigned short*)(ws);
    float*          T  = (float*)(ws + (8u << 20));
    const bool big = ws_size >= (50ull << 20);
    unsigned short* xb = (unsigned short*)(ws + (10u << 20));
    unsigned short* h  = (unsigned short*)(ws + (big ? (18u << 20) : (10u << 20)));

    // ---- layer 1: in (8,16,8) -> out (16,16,16)
    build_T<8, 16><<<2048, 256, 0, stream>>>(fc1_c1, fc1_c2, T);
    build_W<8, 16, 8, 16, 16, 16><<<2048, 256, 0, stream>>>(fc1_c0, T, W);
    if (big) {
        cvt_f32_bf16<<<2048, 256, 0, stream>>>(x, xb);
        // GEMM1: 64x128 dbuf, grid 32x64 = 2048 blocks
        gemm_bias_act<64, 128, 1024, true, false, false>
            <<<dim3(32, 64), 256, 0, stream>>>(xb, W, fc1_b, h, 4096);
    } else {
        gemm_bias_act<64, 128, 1024, true, true, false>
            <<<dim3(32, 64), 256, 0, stream>>>(x, W, fc1_b, h, 4096);
    }

    // ---- layer 2: in (16,16,16) -> out (8,16,8)
    build_T<16, 8><<<2048, 256, 0, stream>>>(fc2_c1, fc2_c2, T);
    build_W<16, 16, 16, 8, 16, 8><<<1024, 256, 0, stream>>>(fc2_c0, T, W);
    // GEMM2: 64x128 dbuf, grid 8x64 = 512 blocks
    gemm_bias_act<64, 128, 4096, false, false, true>
        <<<dim3(8, 64), 256, 0, stream>>>(h, W, fc2_b, d_out, 1024);
}

// Round 12
// 239.697 us; speedup vs baseline: 2.2900x; 1.0020x over previous
//
#include <hip/hip_runtime.h>
#include <stdint.h>

// ---------- bf16 helpers (storage = unsigned short) ----------
__device__ __forceinline__ float b2f(unsigned short u) {
    union { uint32_t i; float f; } v; v.i = ((uint32_t)u) << 16; return v.f;
}
__device__ __forceinline__ unsigned short f2b(float f) {
    union { float f; uint32_t i; } v; v.f = f;
    uint32_t r = v.i + 0x7fffu + ((v.i >> 16) & 1u);   // RNE
    return (unsigned short)(r >> 16);
}

typedef __bf16 bf16x8 __attribute__((ext_vector_type(8)));
typedef float  f32x4  __attribute__((ext_vector_type(4)));
typedef float  f32x16 __attribute__((ext_vector_type(16)));

// ---------------------------------------------------------------------------
// cvt: xb = bf16(x), 8 elems/thread.
// ---------------------------------------------------------------------------
__global__ __launch_bounds__(256)
void cvt_f32_bf16(const float* __restrict__ x, unsigned short* __restrict__ xb) {
    int t = blockIdx.x * 256 + threadIdx.x;
    const float4* p = (const float4*)(x + (size_t)t * 8);
    float4 f0 = p[0], f1 = p[1];
    int4 o;
    o.x = (uint32_t)f2b(f0.x) | ((uint32_t)f2b(f0.y) << 16);
    o.y = (uint32_t)f2b(f0.z) | ((uint32_t)f2b(f0.w) << 16);
    o.z = (uint32_t)f2b(f1.x) | ((uint32_t)f2b(f1.y) << 16);
    o.w = (uint32_t)f2b(f1.z) | ((uint32_t)f2b(f1.w) << 16);
    ((int4*)xb)[t] = o;
}

// ---------------------------------------------------------------------------
// build_T: T[rm=(r1*16+n2)*16+m2][n3][m3] = sum_r2 c1[rm][r2]*c2[(r2*N3+n3)*M3+m3]
// ---------------------------------------------------------------------------
template<int N3, int M3>
__global__ void build_T(const float* __restrict__ c1,
                        const float* __restrict__ c2,
                        float* __restrict__ T) {
    int e = blockIdx.x * 256 + threadIdx.x;
    int m3 = e % M3;
    int t  = e / M3;
    int n3 = t % N3;
    int rm = t / N3;
    float s = 0.f;
#pragma unroll
    for (int r2 = 0; r2 < 16; ++r2)
        s += c1[rm * 16 + r2] * c2[(r2 * N3 + n3) * M3 + m3];
    T[e] = s;
}

// ---------------------------------------------------------------------------
// build_W (coalesced remap): thread t = (((n1*M1+m1)*N2+n2)*M2+m2)*M3+m3.
// ---------------------------------------------------------------------------
template<int N1, int N2, int N3, int M1, int M2, int M3>
__global__ __launch_bounds__(256)
void build_W(const float* __restrict__ c0,
             const float* __restrict__ T,
             unsigned short* __restrict__ W) {
    constexpr int K = N1 * N2 * N3;
    int t  = blockIdx.x * 256 + threadIdx.x;
    int m3 = t % M3;
    int m2 = (t / M3) % M2;
    int n2 = (t / (M3 * M2)) % N2;
    int m1 = (t / (M3 * M2 * N2)) % M1;
    int n1 =  t / (M3 * M2 * N2 * M1);

    float c0r[16];
    const float4* c0p = (const float4*)(c0 + (n1 * M1 + m1) * 16);
#pragma unroll
    for (int i = 0; i < 4; ++i) ((float4*)c0r)[i] = c0p[i];

    float acc[N3] = {};
#pragma unroll
    for (int r1 = 0; r1 < 16; ++r1) {
        const float* Tp = T + (size_t)(((r1 * 16 + n2) * 16 + m2) * N3) * M3 + m3;
#pragma unroll
        for (int n3 = 0; n3 < N3; ++n3)
            acc[n3] += c0r[r1] * Tp[n3 * M3];
    }

    unsigned short ob[N3];
#pragma unroll
    for (int n3 = 0; n3 < N3; ++n3) ob[n3] = f2b(acc[n3]);

    unsigned short* dst = W + (size_t)((m1 * M2 + m2) * M3 + m3) * K
                            + (n1 * N2 + n2) * N3;
#pragma unroll
    for (int c = 0; c < N3 / 8; ++c)
        ((int4*)dst)[c] = ((const int4*)ob)[c];
}

// ---------------------------------------------------------------------------
// GEMM-32: 32x32x16 MFMA variant. BM=BN=128, BK=64, single-buffered,
// register staging, 2x2 waves, wave tile 64x64 = 2x2 frags of 32x32.
// Per b128 fragment read: 2x the MACs of the 16x16 path -> LDS traffic/MAC
// 0.0625 B (was 0.094), MFMA instr count halved, ds_read count -33%.
// A/B operand mapping: idx=lane&31, k-chunk=(lane>>5)*8+j  (consistent
// k-permutation between A and B cancels in the dot product).
// C/D mapping (m74/m101-verified): col=lane&31, row=(reg&3)+8*(reg>>2)+4*(lane>>5).
// XOR-swizzled LDS: global chunk g stored at slot g^(row&7).
// ---------------------------------------------------------------------------
template<int KTOT, bool DO_GELU, bool A_F32, bool C_F32>
__global__ __launch_bounds__(256)
void gemm32_bias_act(const void* __restrict__ Av,
                     const unsigned short* __restrict__ Bt,
                     const float* __restrict__ bias,
                     void* __restrict__ Cv,
                     int Ncols) {
    constexpr int BK = 64;
    __shared__ unsigned short As[128 * BK];   // 16 KB
    __shared__ unsigned short Bs[128 * BK];   // 16 KB

    const int tid  = threadIdx.x;
    const int lane = tid & 63;
    const int wave = tid >> 6;
    const int rowBase = blockIdx.y * 128;
    const int colBase = blockIdx.x * 128;

    const int waveM = (wave >> 1) * 64;
    const int waveN = (wave & 1) * 64;

    f32x16 acc[2][2] = {};

    const int lr    = lane >> 3;          // local row within 8-row chunk
    const int jj    = lane & 7;           // LDS store slot
    const int jglob = jj ^ lr;            // swizzled global chunk
    const int m32   = lane & 31;          // MFMA row/col index
    const int khalf = lane >> 5;          // 0/1: which K-half of the 16
    const int rkey  = lane & 7;           // read swizzle key (= row&7)

    for (int k0 = 0; k0 < KTOT; k0 += BK) {
        // ---- stage A+B: 16 chunks each, 4 per wave
#pragma unroll
        for (int it = 0; it < 4; ++it) {
            const int c = wave * 4 + it;
            const size_t aoff = (size_t)(rowBase + c * 8 + lr) * KTOT + k0 + jglob * 8;
            int4 v;
            if (A_F32) {
                const float* ga = (const float*)Av + aoff;
                float4 f0 = *(const float4*)ga;
                float4 f1 = *(const float4*)(ga + 4);
                v.x = (uint32_t)f2b(f0.x) | ((uint32_t)f2b(f0.y) << 16);
                v.y = (uint32_t)f2b(f0.z) | ((uint32_t)f2b(f0.w) << 16);
                v.z = (uint32_t)f2b(f1.x) | ((uint32_t)f2b(f1.y) << 16);
                v.w = (uint32_t)f2b(f1.z) | ((uint32_t)f2b(f1.w) << 16);
            } else {
                v = *(const int4*)((const unsigned short*)Av + aoff);
            }
            *(int4*)&As[c * 512 + lane * 8] = v;
            *(int4*)&Bs[c * 512 + lane * 8] =
                *(const int4*)(Bt + (size_t)(colBase + c * 8 + lr) * KTOT + k0 + jglob * 8);
        }
        __syncthreads();

        // ---- compute: 4 K-steps of 16; per step 2+2 frag reads, 4 MFMAs
#pragma unroll
        for (int ks = 0; ks < 4; ++ks) {
            const int jswz = ((ks * 2 + khalf) ^ rkey) * 8;
            bf16x8 a_f[2], b_f[2];
#pragma unroll
            for (int i = 0; i < 2; ++i)
                a_f[i] = *(const bf16x8*)&As[(waveM + i * 32 + m32) * BK + jswz];
#pragma unroll
            for (int j = 0; j < 2; ++j)
                b_f[j] = *(const bf16x8*)&Bs[(waveN + j * 32 + m32) * BK + jswz];
#pragma unroll
            for (int i = 0; i < 2; ++i)
#pragma unroll
                for (int j = 0; j < 2; ++j)
                    acc[i][j] = __builtin_amdgcn_mfma_f32_32x32x16_bf16(
                        a_f[i], b_f[j], acc[i][j], 0, 0, 0);
        }
        __syncthreads();
    }

    // Epilogue: 32x32 C/D layout: col=lane&31, row=(reg&3)+8*(reg>>2)+4*(lane>>5)
#pragma unroll
    for (int i = 0; i < 2; ++i) {
#pragma unroll
        for (int j = 0; j < 2; ++j) {
            const int col = colBase + waveN + j * 32 + m32;
            const float bv = bias[col];
#pragma unroll
            for (int reg = 0; reg < 16; ++reg) {
                const int row = rowBase + waveM + i * 32 +
                                (reg & 3) + 8 * (reg >> 2) + 4 * khalf;
                float z = acc[i][j][reg] + bv;
                if (DO_GELU)
                    z = 0.5f * z * (1.f + erff(z * 0.70710678118654752f));
                const size_t off = (size_t)row * Ncols + col;
                if (C_F32) ((float*)Cv)[off] = z;
                else       ((unsigned short*)Cv)[off] = f2b(z);
            }
        }
    }
}

// ---------------------------------------------------------------------------
// GEMM-16 (R11 config, proven): 16x16x32 MFMA, BM=64 x BN=128, BK=64,
// double-buffered LDS, register staging, XOR swizzle.
// ---------------------------------------------------------------------------
#define COMPUTE_TILE(BUF)                                                     \
    {                                                                         \
        _Pragma("unroll")                                                     \
        for (int ks = 0; ks < 2; ++ks) {                                      \
            const int jswz = ((ks * 4 + kc) ^ rkey) * 8;                      \
            bf16x8 a_f[FI], b_f[FJ];                                          \
            _Pragma("unroll")                                                 \
            for (int i = 0; i < FI; ++i)                                      \
                a_f[i] = *(const bf16x8*)&As[(BUF) * ASZ +                    \
                          (waveM + i * 16 + mrow) * BK + jswz];               \
            _Pragma("unroll")                                                 \
            for (int j = 0; j < FJ; ++j)                                      \
                b_f[j] = *(const bf16x8*)&Bs[(BUF) * BSZ +                    \
                          (waveN + j * 16 + mrow) * BK + jswz];               \
            _Pragma("unroll")                                                 \
            for (int i = 0; i < FI; ++i)                                      \
                _Pragma("unroll")                                             \
                for (int j = 0; j < FJ; ++j)                                  \
                    acc[i][j] = __builtin_amdgcn_mfma_f32_16x16x32_bf16(      \
                        a_f[i], b_f[j], acc[i][j], 0, 0, 0);                  \
        }                                                                     \
    }

template<int BM, int BN, int KTOT, bool DO_GELU, bool A_F32, bool C_F32>
__global__ __launch_bounds__(256)
void gemm_bias_act(const void* __restrict__ Av,
                   const unsigned short* __restrict__ Bt,
                   const float* __restrict__ bias,
                   void* __restrict__ Cv,
                   int Ncols) {
    constexpr int BK  = 64;
    constexpr int FI  = BM / 32;
    constexpr int FJ  = BN / 32;
    constexpr int ASZ = BM * BK;
    constexpr int BSZ = BN * BK;
    __shared__ unsigned short As[2 * ASZ];
    __shared__ unsigned short Bs[2 * BSZ];

    const int tid  = threadIdx.x;
    const int lane = tid & 63;
    const int wave = tid >> 6;
    const int rowBase = blockIdx.y * BM;
    const int colBase = blockIdx.x * BN;

    const int waveM = (wave >> 1) * (BM / 2);
    const int waveN = (wave & 1) * (BN / 2);

    f32x4 acc[FI][FJ] = {};

    const int lr    = lane >> 3;
    const int jj    = lane & 7;
    const int jglob = jj ^ lr;
    const int mrow  = lane & 15;
    const int kc    = lane >> 4;
    const int rkey  = mrow & 7;

    const size_t aRowOff = (size_t)(rowBase + lr) * KTOT + jglob * 8;
    const size_t bRowOff = (size_t)(colBase + lr) * KTOT + jglob * 8;

    // ---- prologue
    {
#pragma unroll
        for (int it = 0; it < FI; ++it) {
            const int c = wave * FI + it;
            const size_t aoff = aRowOff + (size_t)(c * 8) * KTOT;
            int4 v;
            if (A_F32) {
                const float* ga = (const float*)Av + aoff;
                float4 f0 = *(const float4*)ga;
                float4 f1 = *(const float4*)(ga + 4);
                v.x = (uint32_t)f2b(f0.x) | ((uint32_t)f2b(f0.y) << 16);
                v.y = (uint32_t)f2b(f0.z) | ((uint32_t)f2b(f0.w) << 16);
                v.z = (uint32_t)f2b(f1.x) | ((uint32_t)f2b(f1.y) << 16);
                v.w = (uint32_t)f2b(f1.z) | ((uint32_t)f2b(f1.w) << 16);
            } else {
                v = *(const int4*)((const unsigned short*)Av + aoff);
            }
            *(int4*)&As[c * 512 + lane * 8] = v;
        }
#pragma unroll
        for (int it = 0; it < FJ; ++it) {
            const int c = wave * FJ + it;
            *(int4*)&Bs[c * 512 + lane * 8] =
                *(const int4*)(Bt + bRowOff + (size_t)(c * 8) * KTOT);
        }
    }
    __syncthreads();

    int cur = 0;
    for (int k0 = BK; k0 < KTOT; k0 += BK) {
        int4 aR[FI], bR[FJ];
#pragma unroll
        for (int it = 0; it < FI; ++it) {
            const int c = wave * FI + it;
            const size_t aoff = aRowOff + (size_t)(c * 8) * KTOT + k0;
            if (A_F32) {
                const float* ga = (const float*)Av + aoff;
                float4 f0 = *(const float4*)ga;
                float4 f1 = *(const float4*)(ga + 4);
                int4 v;
                v.x = (uint32_t)f2b(f0.x) | ((uint32_t)f2b(f0.y) << 16);
                v.y = (uint32_t)f2b(f0.z) | ((uint32_t)f2b(f0.w) << 16);
                v.z = (uint32_t)f2b(f1.x) | ((uint32_t)f2b(f1.y) << 16);
                v.w = (uint32_t)f2b(f1.z) | ((uint32_t)f2b(f1.w) << 16);
                aR[it] = v;
            } else {
                aR[it] = *(const int4*)((const unsigned short*)Av + aoff);
            }
        }
#pragma unroll
        for (int it = 0; it < FJ; ++it) {
            const int c = wave * FJ + it;
            bR[it] = *(const int4*)(Bt + bRowOff + (size_t)(c * 8) * KTOT + k0);
        }

        COMPUTE_TILE(cur)

#pragma unroll
        for (int it = 0; it < FI; ++it) {
            const int c = wave * FI + it;
            *(int4*)&As[(cur ^ 1) * ASZ + c * 512 + lane * 8] = aR[it];
        }
#pragma unroll
        for (int it = 0; it < FJ; ++it) {
            const int c = wave * FJ + it;
            *(int4*)&Bs[(cur ^ 1) * BSZ + c * 512 + lane * 8] = bR[it];
        }
        __syncthreads();
        cur ^= 1;
    }

    COMPUTE_TILE(cur)

    const int cRow = (lane >> 4) * 4;
    const int cCol = lane & 15;
#pragma unroll
    for (int i = 0; i < FI; ++i) {
#pragma unroll
        for (int j = 0; j < FJ; ++j) {
            const int col = colBase + waveN + j * 16 + cCol;
            const float bv = bias[col];
#pragma unroll
            for (int r = 0; r < 4; ++r) {
                const int row = rowBase + waveM + i * 16 + cRow + r;
                float z = acc[i][j][r] + bv;
                if (DO_GELU)
                    z = 0.5f * z * (1.f + erff(z * 0.70710678118654752f));
                const size_t off = (size_t)row * Ncols + col;
                if (C_F32) ((float*)Cv)[off] = z;
                else       ((unsigned short*)Cv)[off] = f2b(z);
            }
        }
    }
}

// ---------------------------------------------------------------------------
extern "C" void kernel_launch(void* const* d_in, const int* in_sizes, int n_in,
                              void* d_out, int out_size, void* d_ws, size_t ws_size,
                              hipStream_t stream) {
    const float* x      = (const float*)d_in[0];   // [4096,1024] fp32
    const float* fc1_c0 = (const float*)d_in[1];
    const float* fc1_c1 = (const float*)d_in[2];
    const float* fc1_c2 = (const float*)d_in[3];
    const float* fc1_b  = (const float*)d_in[4];
    const float* fc2_c0 = (const float*)d_in[5];
    const float* fc2_c1 = (const float*)d_in[6];
    const float* fc2_c2 = (const float*)d_in[7];
    const float* fc2_b  = (const float*)d_in[8];

    // Workspace layout (50 MB preferred):
    //   [0,8M)   W    bf16 — W1t [4096][1024], later W2t [1024][4096]
    //   [8,10M)  T    f32 scratch
    //   [10,18M) xb   bf16 copy of x
    //   [18,50M) h    bf16 [4096][4096]
    // Fallback (<50 MB): no xb; GEMM1 repacks fp32 A in-kernel.
    char* ws = (char*)d_ws;
    unsigned short* W  = (unsigned short*)(ws);
    float*          T  = (float*)(ws + (8u << 20));
    const bool big = ws_size >= (50ull << 20);
    unsigned short* xb = (unsigned short*)(ws + (10u << 20));
    unsigned short* h  = (unsigned short*)(ws + (big ? (18u << 20) : (10u << 20)));

    // ---- layer 1: in (8,16,8) -> out (16,16,16)
    build_T<8, 16><<<2048, 256, 0, stream>>>(fc1_c1, fc1_c2, T);
    build_W<8, 16, 8, 16, 16, 16><<<2048, 256, 0, stream>>>(fc1_c0, T, W);
    if (big) {
        cvt_f32_bf16<<<2048, 256, 0, stream>>>(x, xb);
        // GEMM1: 32x32x16 MFMA, 128x128 tile, grid 32x32 = 1024 blocks
        gemm32_bias_act<1024, true, false, false>
            <<<dim3(32, 32), 256, 0, stream>>>(xb, W, fc1_b, h, 4096);
    } else {
        gemm32_bias_act<1024, true, true, false>
            <<<dim3(32, 32), 256, 0, stream>>>(x, W, fc1_b, h, 4096);
    }

    // ---- layer 2: in (16,16,16) -> out (8,16,8)
    build_T<16, 8><<<2048, 256, 0, stream>>>(fc2_c1, fc2_c2, T);
    build_W<16, 16, 16, 8, 16, 8><<<1024, 256, 0, stream>>>(fc2_c0, T, W);
    // GEMM2: 16x16x32 path, 64x128 dbuf, grid 8x64 = 512 blocks (R11-proven)
    gemm_bias_act<64, 128, 4096, false, false, true>
        <<<dim3(8, 64), 256, 0, stream>>>(h, W, fc2_b, d_out, 1024);
}

// Round 13
// 222.372 us; speedup vs baseline: 2.4685x; 1.0779x over previous
//
#include <hip/hip_runtime.h>
#include <stdint.h>

// ---------- bf16 helpers (storage = unsigned short) ----------
__device__ __forceinline__ float b2f(unsigned short u) {
    union { uint32_t i; float f; } v; v.i = ((uint32_t)u) << 16; return v.f;
}
__device__ __forceinline__ unsigned short f2b(float f) {
    union { float f; uint32_t i; } v; v.f = f;
    uint32_t r = v.i + 0x7fffu + ((v.i >> 16) & 1u);   // RNE
    return (unsigned short)(r >> 16);
}

typedef __bf16 bf16x8 __attribute__((ext_vector_type(8)));
typedef float  f32x16 __attribute__((ext_vector_type(16)));

// ---------------------------------------------------------------------------
// cvt: xb = bf16(x), 8 elems/thread.
// ---------------------------------------------------------------------------
__global__ __launch_bounds__(256)
void cvt_f32_bf16(const float* __restrict__ x, unsigned short* __restrict__ xb) {
    int t = blockIdx.x * 256 + threadIdx.x;
    const float4* p = (const float4*)(x + (size_t)t * 8);
    float4 f0 = p[0], f1 = p[1];
    int4 o;
    o.x = (uint32_t)f2b(f0.x) | ((uint32_t)f2b(f0.y) << 16);
    o.y = (uint32_t)f2b(f0.z) | ((uint32_t)f2b(f0.w) << 16);
    o.z = (uint32_t)f2b(f1.x) | ((uint32_t)f2b(f1.y) << 16);
    o.w = (uint32_t)f2b(f1.z) | ((uint32_t)f2b(f1.w) << 16);
    ((int4*)xb)[t] = o;
}

// ---------------------------------------------------------------------------
// build_T: T[rm=(r1*16+n2)*16+m2][n3][m3] = sum_r2 c1[rm][r2]*c2[(r2*N3+n3)*M3+m3]
// ---------------------------------------------------------------------------
template<int N3, int M3>
__global__ void build_T(const float* __restrict__ c1,
                        const float* __restrict__ c2,
                        float* __restrict__ T) {
    int e = blockIdx.x * 256 + threadIdx.x;
    int m3 = e % M3;
    int t  = e / M3;
    int n3 = t % N3;
    int rm = t / N3;
    float s = 0.f;
#pragma unroll
    for (int r2 = 0; r2 < 16; ++r2)
        s += c1[rm * 16 + r2] * c2[(r2 * N3 + n3) * M3 + m3];
    T[e] = s;
}

// ---------------------------------------------------------------------------
// build_W (coalesced remap): thread t = (((n1*M1+m1)*N2+n2)*M2+m2)*M3+m3.
// ---------------------------------------------------------------------------
template<int N1, int N2, int N3, int M1, int M2, int M3>
__global__ __launch_bounds__(256)
void build_W(const float* __restrict__ c0,
             const float* __restrict__ T,
             unsigned short* __restrict__ W) {
    constexpr int K = N1 * N2 * N3;
    int t  = blockIdx.x * 256 + threadIdx.x;
    int m3 = t % M3;
    int m2 = (t / M3) % M2;
    int n2 = (t / (M3 * M2)) % N2;
    int m1 = (t / (M3 * M2 * N2)) % M1;
    int n1 =  t / (M3 * M2 * N2 * M1);

    float c0r[16];
    const float4* c0p = (const float4*)(c0 + (n1 * M1 + m1) * 16);
#pragma unroll
    for (int i = 0; i < 4; ++i) ((float4*)c0r)[i] = c0p[i];

    float acc[N3] = {};
#pragma unroll
    for (int r1 = 0; r1 < 16; ++r1) {
        const float* Tp = T + (size_t)(((r1 * 16 + n2) * 16 + m2) * N3) * M3 + m3;
#pragma unroll
        for (int n3 = 0; n3 < N3; ++n3)
            acc[n3] += c0r[r1] * Tp[n3 * M3];
    }

    unsigned short ob[N3];
#pragma unroll
    for (int n3 = 0; n3 < N3; ++n3) ob[n3] = f2b(acc[n3]);

    unsigned short* dst = W + (size_t)((m1 * M2 + m2) * M3 + m3) * K
                            + (n1 * N2 + n2) * N3;
#pragma unroll
    for (int c = 0; c < N3 / 8; ++c)
        ((int4*)dst)[c] = ((const int4*)ob)[c];
}

// ---------------------------------------------------------------------------
// Producer-consumer GEMM: C[M][N] = A[M][K]*Bt[N][K]^T + bias, opt. GELU.
// 512 threads: waves 0-3 CONSUME (2x2 wave grid, (BM/2)x(BN/2) each, 32x32x16
// MFMA, FIxFJ frags), waves 4-7 PRODUCE (global->reg->LDS, double-buffered).
// One __syncthreads per K-iter, equal counts both roles. Consumers never wait
// on vmcnt; producers absorb load latency during consumer MFMA.
// LDS swizzle: chunk g of row r stored at slot g ^ key(r),
//   key(r) = (r&7) ^ ((r>>3)&7)  — store side: jj^lr^(c&7); decouples the
//   4-lane same-slot groups that caused R12's 4.19e6 conflicts.
// Register staging only (global_load_lds corrupts at >4 blocks/CU — R7/R8).
// C/D mapping (m74/m101): col=lane&31, row=(reg&3)+8*(reg>>2)+4*(lane>>5).
// ---------------------------------------------------------------------------
#define PC_COMPUTE(BUF)                                                       \
    {                                                                         \
        _Pragma("unroll")                                                     \
        for (int ks = 0; ks < 4; ++ks) {                                      \
            bf16x8 a_f[FI], b_f[FJ];                                          \
            _Pragma("unroll")                                                 \
            for (int i = 0; i < FI; ++i) {                                    \
                const int key = (m32 & 7) ^                                   \
                    (((waveM >> 3) + 4 * i + (m32 >> 3)) & 7);                \
                const int slot = ((ks * 2 + khalf) ^ key) * 8;                \
                a_f[i] = *(const bf16x8*)&As[(BUF) * ASZ +                    \
                          (waveM + i * 32 + m32) * BK + slot];                \
            }                                                                 \
            _Pragma("unroll")                                                 \
            for (int j = 0; j < FJ; ++j) {                                    \
                const int key = (m32 & 7) ^                                   \
                    (((waveN >> 3) + 4 * j + (m32 >> 3)) & 7);                \
                const int slot = ((ks * 2 + khalf) ^ key) * 8;                \
                b_f[j] = *(const bf16x8*)&Bs[(BUF) * BSZ +                    \
                          (waveN + j * 32 + m32) * BK + slot];                \
            }                                                                 \
            _Pragma("unroll")                                                 \
            for (int i = 0; i < FI; ++i)                                      \
                _Pragma("unroll")                                             \
                for (int j = 0; j < FJ; ++j)                                  \
                    acc[i][j] = __builtin_amdgcn_mfma_f32_32x32x16_bf16(      \
                        a_f[i], b_f[j], acc[i][j], 0, 0, 0);                  \
        }                                                                     \
    }

template<int BM, int BN, int KTOT, bool DO_GELU, bool A_F32, bool C_F32>
__global__ __launch_bounds__(512, 4)
void gemm_pc(const void* __restrict__ Av,
             const unsigned short* __restrict__ Bt,
             const float* __restrict__ bias,
             void* __restrict__ Cv,
             int Ncols) {
    constexpr int BK  = 64;
    constexpr int CA  = BM / 8;          // A chunks per tile
    constexpr int CB  = BN / 8;          // B chunks per tile
    constexpr int PA  = CA / 4;          // A chunks per producer wave
    constexpr int PB  = CB / 4;          // B chunks per producer wave
    constexpr int FI  = BM / 64;
    constexpr int FJ  = BN / 64;
    constexpr int ASZ = BM * BK;
    constexpr int BSZ = BN * BK;
    __shared__ unsigned short As[2 * ASZ];
    __shared__ unsigned short Bs[2 * BSZ];

    const int tid  = threadIdx.x;
    const int lane = tid & 63;
    const int wave = tid >> 6;
    const int rowBase = blockIdx.y * BM;
    const int colBase = blockIdx.x * BN;

    const int lr    = lane >> 3;          // local row within 8-row chunk
    const int jj    = lane & 7;           // LDS store slot
    const int m32   = lane & 31;
    const int khalf = lane >> 5;

    if (wave >= 4) {
        // ================= PRODUCER =================
        const int pw = wave - 4;

        // ---- stage tile 0 -> buffer 0
#pragma unroll
        for (int it = 0; it < PA; ++it) {
            const int c  = pw * PA + it;
            const int jg = jj ^ lr ^ (c & 7);
            const size_t aoff = (size_t)(rowBase + c * 8 + lr) * KTOT + jg * 8;
            int4 v;
            if (A_F32) {
                const float* ga = (const float*)Av + aoff;
                float4 f0 = *(const float4*)ga;
                float4 f1 = *(const float4*)(ga + 4);
                v.x = (uint32_t)f2b(f0.x) | ((uint32_t)f2b(f0.y) << 16);
                v.y = (uint32_t)f2b(f0.z) | ((uint32_t)f2b(f0.w) << 16);
                v.z = (uint32_t)f2b(f1.x) | ((uint32_t)f2b(f1.y) << 16);
                v.w = (uint32_t)f2b(f1.z) | ((uint32_t)f2b(f1.w) << 16);
            } else {
                v = *(const int4*)((const unsigned short*)Av + aoff);
            }
            *(int4*)&As[c * 512 + lane * 8] = v;
        }
#pragma unroll
        for (int it = 0; it < PB; ++it) {
            const int c  = pw * PB + it;
            const int jg = jj ^ lr ^ (c & 7);
            *(int4*)&Bs[c * 512 + lane * 8] =
                *(const int4*)(Bt + (size_t)(colBase + c * 8 + lr) * KTOT + jg * 8);
        }
        __syncthreads();

        int buf = 1;
        for (int k0 = BK; k0 < KTOT; k0 += BK) {
            int4 aR[PA], bR[PB];
#pragma unroll
            for (int it = 0; it < PA; ++it) {
                const int c  = pw * PA + it;
                const int jg = jj ^ lr ^ (c & 7);
                const size_t aoff = (size_t)(rowBase + c * 8 + lr) * KTOT + k0 + jg * 8;
                if (A_F32) {
                    const float* ga = (const float*)Av + aoff;
                    float4 f0 = *(const float4*)ga;
                    float4 f1 = *(const float4*)(ga + 4);
                    int4 v;
                    v.x = (uint32_t)f2b(f0.x) | ((uint32_t)f2b(f0.y) << 16);
                    v.y = (uint32_t)f2b(f0.z) | ((uint32_t)f2b(f0.w) << 16);
                    v.z = (uint32_t)f2b(f1.x) | ((uint32_t)f2b(f1.y) << 16);
                    v.w = (uint32_t)f2b(f1.z) | ((uint32_t)f2b(f1.w) << 16);
                    aR[it] = v;
                } else {
                    aR[it] = *(const int4*)((const unsigned short*)Av + aoff);
                }
            }
#pragma unroll
            for (int it = 0; it < PB; ++it) {
                const int c  = pw * PB + it;
                const int jg = jj ^ lr ^ (c & 7);
                bR[it] = *(const int4*)(Bt + (size_t)(colBase + c * 8 + lr) * KTOT + k0 + jg * 8);
            }
#pragma unroll
            for (int it = 0; it < PA; ++it) {
                const int c = pw * PA + it;
                *(int4*)&As[buf * ASZ + c * 512 + lane * 8] = aR[it];
            }
#pragma unroll
            for (int it = 0; it < PB; ++it) {
                const int c = pw * PB + it;
                *(int4*)&Bs[buf * BSZ + c * 512 + lane * 8] = bR[it];
            }
            __syncthreads();
            buf ^= 1;
        }
    } else {
        // ================= CONSUMER =================
        const int waveM = (wave >> 1) * (BM / 2);
        const int waveN = (wave & 1) * (BN / 2);
        f32x16 acc[FI][FJ] = {};

        __syncthreads();                 // wait for tile 0

        int cur = 0;
        for (int k0 = BK; k0 < KTOT; k0 += BK) {
            PC_COMPUTE(cur)
            __syncthreads();
            cur ^= 1;
        }
        PC_COMPUTE(cur)

        // Epilogue: col=lane&31, row=(reg&3)+8*(reg>>2)+4*khalf
#pragma unroll
        for (int i = 0; i < FI; ++i) {
#pragma unroll
            for (int j = 0; j < FJ; ++j) {
                const int col = colBase + waveN + j * 32 + m32;
                const float bv = bias[col];
#pragma unroll
                for (int reg = 0; reg < 16; ++reg) {
                    const int row = rowBase + waveM + i * 32 +
                                    (reg & 3) + 8 * (reg >> 2) + 4 * khalf;
                    float z = acc[i][j][reg] + bv;
                    if (DO_GELU)
                        z = 0.5f * z * (1.f + erff(z * 0.70710678118654752f));
                    const size_t off = (size_t)row * Ncols + col;
                    if (C_F32) ((float*)Cv)[off] = z;
                    else       ((unsigned short*)Cv)[off] = f2b(z);
                }
            }
        }
    }
}

// ---------------------------------------------------------------------------
extern "C" void kernel_launch(void* const* d_in, const int* in_sizes, int n_in,
                              void* d_out, int out_size, void* d_ws, size_t ws_size,
                              hipStream_t stream) {
    const float* x      = (const float*)d_in[0];   // [4096,1024] fp32
    const float* fc1_c0 = (const float*)d_in[1];
    const float* fc1_c1 = (const float*)d_in[2];
    const float* fc1_c2 = (const float*)d_in[3];
    const float* fc1_b  = (const float*)d_in[4];
    const float* fc2_c0 = (const float*)d_in[5];
    const float* fc2_c1 = (const float*)d_in[6];
    const float* fc2_c2 = (const float*)d_in[7];
    const float* fc2_b  = (const float*)d_in[8];

    // Workspace layout (50 MB preferred):
    //   [0,8M)   W    bf16 — W1t [4096][1024], later W2t [1024][4096]
    //   [8,10M)  T    f32 scratch
    //   [10,18M) xb   bf16 copy of x
    //   [18,50M) h    bf16 [4096][4096]
    // Fallback (<50 MB): no xb; GEMM1 repacks fp32 A in-kernel.
    char* ws = (char*)d_ws;
    unsigned short* W  = (unsigned short*)(ws);
    float*          T  = (float*)(ws + (8u << 20));
    const bool big = ws_size >= (50ull << 20);
    unsigned short* xb = (unsigned short*)(ws + (10u << 20));
    unsigned short* h  = (unsigned short*)(ws + (big ? (18u << 20) : (10u << 20)));

    // ---- layer 1: in (8,16,8) -> out (16,16,16)
    build_T<8, 16><<<2048, 256, 0, stream>>>(fc1_c1, fc1_c2, T);
    build_W<8, 16, 8, 16, 16, 16><<<2048, 256, 0, stream>>>(fc1_c0, T, W);
    if (big) {
        cvt_f32_bf16<<<2048, 256, 0, stream>>>(x, xb);
        // GEMM1: producer-consumer, 128x128 tile, grid 32x32, 512 threads
        gemm_pc<128, 128, 1024, true, false, false>
            <<<dim3(32, 32), 512, 0, stream>>>(xb, W, fc1_b, h, 4096);
    } else {
        gemm_pc<128, 128, 1024, true, true, false>
            <<<dim3(32, 32), 512, 0, stream>>>(x, W, fc1_b, h, 4096);
    }

    // ---- layer 2: in (16,16,16) -> out (8,16,8)
    build_T<16, 8><<<2048, 256, 0, stream>>>(fc2_c1, fc2_c2, T);
    build_W<16, 16, 16, 8, 16, 8><<<1024, 256, 0, stream>>>(fc2_c0, T, W);
    // GEMM2: producer-consumer, 128x64 tile, grid 16x32 = 512 blocks
    gemm_pc<128, 64, 4096, false, false, true>
        <<<dim3(16, 32), 512, 0, stream>>>(h, W, fc2_b, d_out, 1024);
}